// Round 17
// baseline (266.411 us; speedup 1.0000x reference)
//
#include <hip/hip_runtime.h>
#include <stdint.h>

// CIN (xDeepFM) forward, MI355X f16-MFMA implementation. Round 17:
//  - r16 shell with __launch_bounds__(512, 2): r10/r15/r16 all proved hipcc
//    treats the 2nd arg like CUDA min-BLOCKS/CU (arg=4 -> 64-VGPR cap ->
//    scratch spill, WRITE_SIZE 8-17MB). (512,2) allocates ~100 VGPRs; at
//    <=128 the HW still runs 4 waves/SIMD, and LDS 66KB -> 2 blocks/CU.
//    This finally tests 4 waves/SIMD spill-free at constant per-CU traffic.
//  - N split across block pairs: 512 blocks x 512 thr; block (bgroup, nhalf)
//    computes M=128 x N=128; 8 waves x 16 cols; co-resident pair stages
//    DISJOINT W halves (per-CU staging = r13).
//  - TILE_BODY verbatim r13 (validated barrier-free pipeline), n-width 1.
//  - xg global xs path with op_sel broadcast, XOR swizzle: unchanged.
// Layers: out[b,d,o] = relu(bias[o] + sum_{f,h'} x0[b,f,d]*h[b,h',d]*W[f*Hp+h',o])
//   layer0: Hp=39 (pad 64), layers1/2: Hp=128. B=1024, F=39, D=32, N=256.

typedef unsigned int u32;
typedef unsigned short u16;
typedef __attribute__((ext_vector_type(8))) unsigned short us8;
typedef __attribute__((ext_vector_type(8))) _Float16 half8;
typedef __attribute__((ext_vector_type(4))) float f32x4;

__device__ __forceinline__ u16 f32_to_f16u(float f) {
  union { _Float16 h; u16 u; } c;
  c.h = (_Float16)f;
  return c.u;
}
// a.{lo,hi} * broadcast(b.lo)
__device__ __forceinline__ u32 pkmul_blo(u32 a, u32 b) {
  u32 r;
  asm("v_pk_mul_f16 %0, %1, %2 op_sel:[0,0] op_sel_hi:[1,0]" : "=v"(r) : "v"(a), "v"(b));
  return r;
}
// a.{lo,hi} * broadcast(b.hi)
__device__ __forceinline__ u32 pkmul_bhi(u32 a, u32 b) {
  u32 r;
  asm("v_pk_mul_f16 %0, %1, %2 op_sel:[0,1] op_sel_hi:[1,1]" : "=v"(r) : "v"(a), "v"(b));
  return r;
}
__device__ __forceinline__ void gload16(const u16* g, u16* l) {
  __builtin_amdgcn_global_load_lds((const __attribute__((address_space(1))) u32*)g,
                                   (__attribute__((address_space(3))) u32*)l, 16, 0, 0);
}
__device__ __forceinline__ void wait_vm0_sb() {
  asm volatile("s_waitcnt vmcnt(0)" ::: "memory");
  __builtin_amdgcn_sched_barrier(0);
}

// ---------------- prep: W (K,256) f32 -> WT (256, KPAD) f16, transposed ------
__global__ void prep_wt(const float* __restrict__ W0, const float* __restrict__ W1,
                        const float* __restrict__ W2, u16* __restrict__ WT0,
                        u16* __restrict__ WT1, u16* __restrict__ WT2) {
  int blk = blockIdx.x;
  const float* W;
  u16* WT;
  int KPAD, kp0;
  bool l0 = false;
  if (blk < 312) { W = W0; WT = WT0; KPAD = 2496; kp0 = blk * 8; l0 = true; }
  else if (blk < 936) { W = W1; WT = WT1; KPAD = 4992; kp0 = (blk - 312) * 8; }
  else { W = W2; WT = WT2; KPAD = 4992; kp0 = (blk - 936) * 8; }

  __shared__ u16 lds[8][257];
  int t = threadIdx.x;  // 256 = n
  #pragma unroll
  for (int kk = 0; kk < 8; ++kk) {
    int kp = kp0 + kk;
    float v;
    if (l0) {
      int f = kp >> 6, hh = kp & 63;
      v = (hh < 39) ? W[(f * 39 + hh) * 256 + t] : 0.f;
    } else {
      v = W[kp * 256 + t];
    }
    lds[kk][t] = f32_to_f16u(v);
  }
  __syncthreads();
  us8 o;
  #pragma unroll
  for (int kk = 0; kk < 8; ++kk) o[kk] = lds[kk][t];
  *(us8*)(&WT[(size_t)t * KPAD + kp0]) = o;
}

// ---------------- prep: x -> xg[bgroup][dl(16)][f(39)][m(8)] f16 -------------
__global__ void prep_xg(const float* __restrict__ x, u16* __restrict__ xg) {
  int bb = blockIdx.x;  // 0..255
  int t = threadIdx.x;  // 256
  for (int idx = t; idx < 4992; idx += 256) {
    int dl = idx / 312;
    int rem = idx - dl * 312;
    int f = rem >> 3, m = rem & 7;
    float v = x[(size_t)(bb * 4 + (m >> 1)) * 1248 + f * 32 + (m & 1) * 16 + dl];
    xg[(size_t)bb * 4992 + idx] = f32_to_f16u(v);
  }
}

// ---------------- main layer kernel ------------------------------------------
// grid 512 x 512 threads. Block (bgroup, nhalf): 4 samples (M=128 rows) x
// 128 cols; 8 waves x 16 cols. K-tile = 64, dbuf LDS, no inner barriers.
template <int LAYER>
__global__ __launch_bounds__(512, 2) void cin_layer(
    const float* __restrict__ x, const u16* __restrict__ hin,
    const u16* __restrict__ WT, const u16* __restrict__ xg,
    const float* __restrict__ bias, u16* __restrict__ hout,
    float* __restrict__ fsum) {
  constexpr int HPAD = (LAYER == 0) ? 64 : 128;
  constexpr int HROW = HPAD + 8;
  constexpr int KPAD = 39 * HPAD;
  constexpr int HC2 = HPAD / 64;  // k64 tiles per f
  constexpr int NT = 39 * HC2;

  __shared__ __align__(16) u16 wtile[2][128 * 64];  // [n_loc][64k] swizzled, dbuf
  __shared__ __align__(16) u16 hT[4][32][HROW];     // h^T f16 [b'][d][h']

  const int tid = threadIdx.x;
  const int bgroup = blockIdx.x >> 1;
  const int nhalf = blockIdx.x & 1;
  const int bbase = bgroup * 4;

  // ---- stage hT (from x for layer 0, from hbuf otherwise)
  if (LAYER == 0) {
    for (int idx = tid; idx < 4 * 1248; idx += 512) {
      int b = idx / 1248;
      int rem = idx - b * 1248;
      int f = rem >> 5, d = rem & 31;
      hT[b][d][f] = f32_to_f16u(x[(bbase + b) * 1248 + rem]);
    }
    for (int idx = tid; idx < 4 * 32 * 25; idx += 512) {  // zero h' in [39,64)
      int b = idx / 800;
      int rem = idx - b * 800;
      int d = rem / 25, p = rem - d * 25;
      hT[b][d][39 + p] = 0;
    }
  } else {
    for (int idx = tid; idx < 4 * 32 * 16; idx += 512) {  // h_buf f16 [b][d][128]
      int b = idx >> 9, rem = idx & 511;
      int d = rem >> 4, c = rem & 15;
      us8 v = *(const us8*)(&hin[(((bbase + b) * 32 + d) << 7) + c * 8]);
      *(us8*)(&hT[b][d][c * 8]) = v;
    }
  }

  const int lane = tid & 63;
  const int w = tid >> 6;  // wave 0..7 -> 16-col slice within this half
  const int l15 = lane & 15;
  const int g = lane >> 4;

  // staging per-lane source (inverse-swizzle): 2 instr/tile, 8 rows each.
  // instr j covers local rows w*16 + j*8 + nloc; chunk qq = slot^nloc
  const int nloc = lane >> 3, slot = lane & 7;
  const int qq = slot ^ nloc;
  const u16* wsrc =
      WT + (size_t)(nhalf * 128 + w * 16 + nloc) * KPAD + qq * 8;  // j adds 8*KPAD

  // B-read base (swizzled): local row = w*16 + l15, row&7 == l15&7
  const int xorm = (l15 & 7) * 8;       // u16 units
  const int rB0 = (w * 16 + l15) * 64;  // local row base
  const u16* xrow = xg + (size_t)bgroup * 4992 + l15 * 312;

  f32x4 acc[8];
  #pragma unroll
  for (int m = 0; m < 8; ++m) acc[m] = (f32x4){0.f, 0.f, 0.f, 0.f};

  // prologue: stage tile 0 (koff=0) into buf 0
  {
    u16* dst = &wtile[0][(w * 16) * 64];
    #pragma unroll
    for (int j = 0; j < 2; ++j)
      gload16(wsrc + (size_t)j * 8 * KPAD, dst + j * 8 * 64);
  }
  __syncthreads();  // covers hT ds-writes AND tile0 (vmcnt0+lgkmcnt0)

  union HF { u32 u[4]; half8 h; us8 s; };
  union XQ { u32 u[4]; us8 s; };

  // chunk-0 h fragments (reused across the 39-f loop)
  HF hf2[8][2];
  #pragma unroll
  for (int m = 0; m < 8; ++m)
    #pragma unroll
    for (int c = 0; c < 2; ++c)
      hf2[m][c].s = *(const us8*)(&hT[m >> 1][(m & 1) * 16 + l15][c * 32 + g * 8]);

  // preload tile-0 B-fragments (from LDS) and xs (from global)
  HF fr[2];
  XQ xqA, xqB;
  #pragma unroll
  for (int c = 0; c < 2; ++c) {
    const int offb = (c * 32 + g * 8) ^ xorm;
    fr[c].s = *(const us8*)(&wtile[0][rB0 + offb]);
  }
  xqA.s = *(const us8*)(xrow);  // f=0

  int f = 0, hc = 0, tt = 0;

#define TILE_BODY(XC, XN)                                                          \
  {                                                                                \
    const int buf = tt & 1;                                                        \
    const bool more = (tt + 1 < NT);                                               \
    int nf = f + 1, nhc = hc;                                                      \
    if (nf == 39) { nf = 0; ++nhc; }                                               \
    if (more) {                                                                    \
      const int koff = nf * HPAD + nhc * 64;                                       \
      u16* dst = &wtile[buf ^ 1][(w * 16) * 64];                                   \
      _Pragma("unroll")                                                            \
      for (int j = 0; j < 2; ++j)                                                  \
        gload16(wsrc + (size_t)j * 8 * KPAD + koff, dst + j * 8 * 64);             \
      XN.s = *(const us8*)(xrow + nf * 8);                                         \
      __builtin_amdgcn_sched_barrier(0);                                           \
    }                                                                              \
    _Pragma("unroll")                                                              \
    for (int c = 0; c < 2; ++c) {                                                  \
      _Pragma("unroll")                                                            \
      for (int m = 0; m < 8; ++m) {                                                \
        HF a;                                                                      \
        _Pragma("unroll")                                                          \
        for (int i = 0; i < 4; ++i)                                                \
          a.u[i] = (m & 1) ? pkmul_bhi(hf2[m][c].u[i], XC.u[m >> 1])               \
                           : pkmul_blo(hf2[m][c].u[i], XC.u[m >> 1]);              \
        acc[m] = __builtin_amdgcn_mfma_f32_16x16x32_f16(a.h, fr[c].h,              \
                                                        acc[m], 0, 0, 0);          \
      }                                                                            \
    }                                                                              \
    if (more) {                                                                    \
      wait_vm0_sb();                                                               \
      _Pragma("unroll")                                                            \
      for (int c = 0; c < 2; ++c) {                                                \
        const int offb = (c * 32 + g * 8) ^ xorm;                                  \
        fr[c].s = *(const us8*)(&wtile[buf ^ 1][rB0 + offb]);                      \
      }                                                                            \
      if (nhc != hc) {                                                             \
        _Pragma("unroll")                                                          \
        for (int m = 0; m < 8; ++m)                                                \
          _Pragma("unroll")                                                        \
          for (int c = 0; c < 2; ++c)                                              \
            hf2[m][c].s = *(const us8*)(                                           \
                &hT[m >> 1][(m & 1) * 16 + l15][(2 * nhc + c) * 32 + g * 8]);      \
      }                                                                            \
    }                                                                              \
    f = nf;                                                                        \
    hc = nhc;                                                                      \
    ++tt;                                                                          \
  }

  for (int p = 0; p < NT / 2; ++p) {
    TILE_BODY(xqA, xqB);
    TILE_BODY(xqB, xqA);
  }
  if (NT & 1) TILE_BODY(xqA, xqB);
#undef TILE_BODY

  // ---- epilogue: relu(acc+bias); o<128 -> h for next layer; else d-sums
  const int o = nhalf * 128 + w * 16 + l15;
  const float bv = bias[o];

  if (LAYER < 2 && nhalf == 0) {  // h half (o in [0,128))
    #pragma unroll
    for (int m = 0; m < 8; ++m)
      #pragma unroll
      for (int r = 0; r < 4; ++r) {
        int row = m * 16 + g * 4 + r;  // C/D: row=(lane>>4)*4+reg, col=lane&15
        int s = row >> 5, d = row & 31;
        float v = fmaxf(acc[m][r] + bv, 0.f);
        hout[(((bbase + s) * 32 + d) << 7) + o] = f32_to_f16u(v);
      }
  } else {  // finals: sum over d per sample, store fsum[b][j]
    float sub[4] = {0.f, 0.f, 0.f, 0.f};
    #pragma unroll
    for (int m = 0; m < 8; ++m)
      #pragma unroll
      for (int r = 0; r < 4; ++r)
        sub[m >> 1] += fmaxf(acc[m][r] + bv, 0.f);
    #pragma unroll
    for (int s = 0; s < 4; ++s) {
      sub[s] += __shfl_xor(sub[s], 16);
      sub[s] += __shfl_xor(sub[s], 32);
    }
    if (lane < 16) {
      int j = (LAYER == 0) ? (o - 128) : ((LAYER == 1) ? o : (256 + o));
      #pragma unroll
      for (int s = 0; s < 4; ++s) fsum[(bbase + s) * 512 + j] = sub[s];
    }
  }
}

// ---------------- finalize: out[b] = fc_b + sum_j fsum[b][j]*fc_w[j] ----------
__global__ void finalize(const float* __restrict__ fsum, const float* __restrict__ fc_w,
                         const float* __restrict__ fc_b, float* __restrict__ out) {
  int b = blockIdx.x;
  int lane = threadIdx.x;  // 64
  const float* fs = fsum + (size_t)b * 512;
  float s = 0.f;
  #pragma unroll
  for (int k = 0; k < 8; ++k) {
    int j = k * 64 + lane;
    s += fs[j] * fc_w[j];
  }
  #pragma unroll
  for (int off = 32; off; off >>= 1) s += __shfl_xor(s, off);
  if (lane == 0) out[b] = s + fc_b[0];
}

extern "C" void kernel_launch(void* const* d_in, const int* in_sizes, int n_in,
                              void* d_out, int out_size, void* d_ws, size_t ws_size,
                              hipStream_t stream) {
  const float* x = (const float*)d_in[0];
  const float* W0 = (const float*)d_in[1];
  const float* b0 = (const float*)d_in[2];
  const float* W1 = (const float*)d_in[3];
  const float* b1 = (const float*)d_in[4];
  const float* W2 = (const float*)d_in[5];
  const float* b2 = (const float*)d_in[6];
  const float* fc_w = (const float*)d_in[7];
  const float* fc_b = (const float*)d_in[8];
  float* out = (float*)d_out;

  char* ws = (char*)d_ws;
  size_t oWT0 = 0;
  size_t oWT1 = oWT0 + (size_t)256 * 2496 * 2;
  size_t oWT2 = oWT1 + (size_t)256 * 4992 * 2;
  size_t oH = oWT2 + (size_t)256 * 4992 * 2;
  size_t oFS = oH + (size_t)1024 * 32 * 128 * 2;
  size_t oXG = oFS + (size_t)1024 * 512 * 4;
  u16* WT0 = (u16*)(ws + oWT0);
  u16* WT1 = (u16*)(ws + oWT1);
  u16* WT2 = (u16*)(ws + oWT2);
  u16* hbuf = (u16*)(ws + oH);
  float* fsum = (float*)(ws + oFS);
  u16* xg = (u16*)(ws + oXG);  // 256*4992*2 = 2.56 MB

  prep_wt<<<1560, 256, 0, stream>>>(W0, W1, W2, WT0, WT1, WT2);
  prep_xg<<<256, 256, 0, stream>>>(x, xg);
  cin_layer<0><<<512, 512, 0, stream>>>(x, nullptr, WT0, xg, b0, hbuf, fsum);
  cin_layer<1><<<512, 512, 0, stream>>>(x, hbuf, WT1, xg, b1, hbuf, fsum);
  cin_layer<2><<<512, 512, 0, stream>>>(x, hbuf, WT2, xg, b2, nullptr, fsum);
  finalize<<<1024, 64, 0, stream>>>(fsum, fc_w, fc_b, out);
}

// Round 18
// 260.051 us; speedup vs baseline: 1.0245x; 1.0245x over previous
//
#include <hip/hip_runtime.h>
#include <stdint.h>

// CIN (xDeepFM) forward, MI355X f16-MFMA implementation. Round 18:
//  - r15 shell with __launch_bounds__(1024, 1): r15 proved the 16-wave block
//    is correct and resident (occupancy 38%) but (1024,4) capped VGPR at 64
//    -> scratch spill (WRITE 17.9MB). (1024,1) caps at 128 (kernel ~100),
//    no spill, and ONE block = guaranteed 16 waves/CU = 4 waves/SIMD with
//    per-CU W-traffic identical to r13. Clean test of bubble coverage.
//  - 256 blocks x 1024 thr; M=128, 16 waves x 16 cols; TILE_BODY verbatim
//    r13 re-dimensioned (2 gload16 + 2 fr reads + 16 MFMA /tile/wave).
//  - xg global xs path with op_sel broadcast, XOR swizzle: unchanged.
// Layers: out[b,d,o] = relu(bias[o] + sum_{f,h'} x0[b,f,d]*h[b,h',d]*W[f*Hp+h',o])
//   layer0: Hp=39 (pad 64), layers1/2: Hp=128. B=1024, F=39, D=32, N=256.

typedef unsigned int u32;
typedef unsigned short u16;
typedef __attribute__((ext_vector_type(8))) unsigned short us8;
typedef __attribute__((ext_vector_type(8))) _Float16 half8;
typedef __attribute__((ext_vector_type(4))) float f32x4;

__device__ __forceinline__ u16 f32_to_f16u(float f) {
  union { _Float16 h; u16 u; } c;
  c.h = (_Float16)f;
  return c.u;
}
// a.{lo,hi} * broadcast(b.lo)
__device__ __forceinline__ u32 pkmul_blo(u32 a, u32 b) {
  u32 r;
  asm("v_pk_mul_f16 %0, %1, %2 op_sel:[0,0] op_sel_hi:[1,0]" : "=v"(r) : "v"(a), "v"(b));
  return r;
}
// a.{lo,hi} * broadcast(b.hi)
__device__ __forceinline__ u32 pkmul_bhi(u32 a, u32 b) {
  u32 r;
  asm("v_pk_mul_f16 %0, %1, %2 op_sel:[0,1] op_sel_hi:[1,1]" : "=v"(r) : "v"(a), "v"(b));
  return r;
}
__device__ __forceinline__ void gload16(const u16* g, u16* l) {
  __builtin_amdgcn_global_load_lds((const __attribute__((address_space(1))) u32*)g,
                                   (__attribute__((address_space(3))) u32*)l, 16, 0, 0);
}
__device__ __forceinline__ void wait_vm0_sb() {
  asm volatile("s_waitcnt vmcnt(0)" ::: "memory");
  __builtin_amdgcn_sched_barrier(0);
}

// ---------------- prep: W (K,256) f32 -> WT (256, KPAD) f16, transposed ------
__global__ void prep_wt(const float* __restrict__ W0, const float* __restrict__ W1,
                        const float* __restrict__ W2, u16* __restrict__ WT0,
                        u16* __restrict__ WT1, u16* __restrict__ WT2) {
  int blk = blockIdx.x;
  const float* W;
  u16* WT;
  int KPAD, kp0;
  bool l0 = false;
  if (blk < 312) { W = W0; WT = WT0; KPAD = 2496; kp0 = blk * 8; l0 = true; }
  else if (blk < 936) { W = W1; WT = WT1; KPAD = 4992; kp0 = (blk - 312) * 8; }
  else { W = W2; WT = WT2; KPAD = 4992; kp0 = (blk - 936) * 8; }

  __shared__ u16 lds[8][257];
  int t = threadIdx.x;  // 256 = n
  #pragma unroll
  for (int kk = 0; kk < 8; ++kk) {
    int kp = kp0 + kk;
    float v;
    if (l0) {
      int f = kp >> 6, hh = kp & 63;
      v = (hh < 39) ? W[(f * 39 + hh) * 256 + t] : 0.f;
    } else {
      v = W[kp * 256 + t];
    }
    lds[kk][t] = f32_to_f16u(v);
  }
  __syncthreads();
  us8 o;
  #pragma unroll
  for (int kk = 0; kk < 8; ++kk) o[kk] = lds[kk][t];
  *(us8*)(&WT[(size_t)t * KPAD + kp0]) = o;
}

// ---------------- prep: x -> xg[bgroup][dl(16)][f(39)][m(8)] f16 -------------
__global__ void prep_xg(const float* __restrict__ x, u16* __restrict__ xg) {
  int bb = blockIdx.x;  // 0..255
  int t = threadIdx.x;  // 256
  for (int idx = t; idx < 4992; idx += 256) {
    int dl = idx / 312;
    int rem = idx - dl * 312;
    int f = rem >> 3, m = rem & 7;
    float v = x[(size_t)(bb * 4 + (m >> 1)) * 1248 + f * 32 + (m & 1) * 16 + dl];
    xg[(size_t)bb * 4992 + idx] = f32_to_f16u(v);
  }
}

// ---------------- main layer kernel ------------------------------------------
// grid 256 x 1024 threads. Block: 4 samples (M=128 rows), 16 waves each
// covering all 128 rows x its own 16-col slice. K-tile = 64, dbuf LDS,
// no inner barriers, 16x16x32 f16 MFMA.
template <int LAYER>
__global__ __launch_bounds__(1024, 1) void cin_layer(
    const float* __restrict__ x, const u16* __restrict__ hin,
    const u16* __restrict__ WT, const u16* __restrict__ xg,
    const float* __restrict__ bias, u16* __restrict__ hout,
    float* __restrict__ fsum) {
  constexpr int HPAD = (LAYER == 0) ? 64 : 128;
  constexpr int HROW = HPAD + 8;
  constexpr int KPAD = 39 * HPAD;
  constexpr int HC2 = HPAD / 64;  // k64 tiles per f
  constexpr int NT = 39 * HC2;

  __shared__ __align__(16) u16 wtile[2][256 * 64];  // [n][64k] swizzled, dbuf
  __shared__ __align__(16) u16 hT[4][32][HROW];     // h^T f16 [b'][d][h']

  const int tid = threadIdx.x;
  const int bbase = blockIdx.x * 4;

  // ---- stage hT (from x for layer 0, from hbuf otherwise)
  if (LAYER == 0) {
    for (int idx = tid; idx < 4 * 1248; idx += 1024) {
      int b = idx / 1248;
      int rem = idx - b * 1248;
      int f = rem >> 5, d = rem & 31;
      hT[b][d][f] = f32_to_f16u(x[(bbase + b) * 1248 + rem]);
    }
    for (int idx = tid; idx < 4 * 32 * 25; idx += 1024) {  // zero h' in [39,64)
      int b = idx / 800;
      int rem = idx - b * 800;
      int d = rem / 25, p = rem - d * 25;
      hT[b][d][39 + p] = 0;
    }
  } else {
    for (int idx = tid; idx < 4 * 32 * 16; idx += 1024) {  // h_buf f16 [b][d][128]
      int b = idx >> 9, rem = idx & 511;
      int d = rem >> 4, c = rem & 15;
      us8 v = *(const us8*)(&hin[(((bbase + b) * 32 + d) << 7) + c * 8]);
      *(us8*)(&hT[b][d][c * 8]) = v;
    }
  }

  const int lane = tid & 63;
  const int w = tid >> 6;  // wave 0..15 -> 16-col slice
  const int l15 = lane & 15;
  const int g = lane >> 4;

  // staging per-lane source (inverse-swizzle): 2 instr/tile, 8 rows each.
  // instr j covers rows w*16 + j*8 + nloc; lane holds slot -> chunk qq=slot^nloc
  const int nloc = lane >> 3, slot = lane & 7;
  const int qq = slot ^ nloc;
  const u16* wsrc = WT + (size_t)(w * 16 + nloc) * KPAD + qq * 8;  // j adds 8*KPAD

  // B-read base (swizzled): row n = w*16 + l15, n&7 == l15&7
  const int xorm = (l15 & 7) * 8;       // u16 units
  const int rB0 = (w * 16 + l15) * 64;  // row base
  const u16* xrow = xg + (size_t)blockIdx.x * 4992 + l15 * 312;

  f32x4 acc[8];
  #pragma unroll
  for (int m = 0; m < 8; ++m) acc[m] = (f32x4){0.f, 0.f, 0.f, 0.f};

  // prologue: stage tile 0 (koff=0) into buf 0
  {
    u16* dst = &wtile[0][(w * 16) * 64];
    #pragma unroll
    for (int j = 0; j < 2; ++j)
      gload16(wsrc + (size_t)j * 8 * KPAD, dst + j * 8 * 64);
  }
  __syncthreads();  // covers hT ds-writes AND tile0 (vmcnt0+lgkmcnt0)

  union HF { u32 u[4]; half8 h; us8 s; };
  union XQ { u32 u[4]; us8 s; };

  // chunk-0 h fragments (reused across the 39-f loop)
  HF hf2[8][2];
  #pragma unroll
  for (int m = 0; m < 8; ++m)
    #pragma unroll
    for (int c = 0; c < 2; ++c)
      hf2[m][c].s = *(const us8*)(&hT[m >> 1][(m & 1) * 16 + l15][c * 32 + g * 8]);

  // preload tile-0 B-fragments (from LDS) and xs (from global)
  HF fr[2];
  XQ xqA, xqB;
  #pragma unroll
  for (int c = 0; c < 2; ++c) {
    const int offb = (c * 32 + g * 8) ^ xorm;
    fr[c].s = *(const us8*)(&wtile[0][rB0 + offb]);
  }
  xqA.s = *(const us8*)(xrow);  // f=0

  int f = 0, hc = 0, tt = 0;

#define TILE_BODY(XC, XN)                                                          \
  {                                                                                \
    const int buf = tt & 1;                                                        \
    const bool more = (tt + 1 < NT);                                               \
    int nf = f + 1, nhc = hc;                                                      \
    if (nf == 39) { nf = 0; ++nhc; }                                               \
    if (more) {                                                                    \
      const int koff = nf * HPAD + nhc * 64;                                       \
      u16* dst = &wtile[buf ^ 1][(w * 16) * 64];                                   \
      _Pragma("unroll")                                                            \
      for (int j = 0; j < 2; ++j)                                                  \
        gload16(wsrc + (size_t)j * 8 * KPAD + koff, dst + j * 8 * 64);             \
      XN.s = *(const us8*)(xrow + nf * 8);                                         \
      __builtin_amdgcn_sched_barrier(0);                                           \
    }                                                                              \
    _Pragma("unroll")                                                              \
    for (int c = 0; c < 2; ++c) {                                                  \
      _Pragma("unroll")                                                            \
      for (int m = 0; m < 8; ++m) {                                                \
        HF a;                                                                      \
        _Pragma("unroll")                                                          \
        for (int i = 0; i < 4; ++i)                                                \
          a.u[i] = (m & 1) ? pkmul_bhi(hf2[m][c].u[i], XC.u[m >> 1])               \
                           : pkmul_blo(hf2[m][c].u[i], XC.u[m >> 1]);              \
        acc[m] = __builtin_amdgcn_mfma_f32_16x16x32_f16(a.h, fr[c].h,              \
                                                        acc[m], 0, 0, 0);          \
      }                                                                            \
    }                                                                              \
    if (more) {                                                                    \
      wait_vm0_sb();                                                               \
      _Pragma("unroll")                                                            \
      for (int c = 0; c < 2; ++c) {                                                \
        const int offb = (c * 32 + g * 8) ^ xorm;                                  \
        fr[c].s = *(const us8*)(&wtile[buf ^ 1][rB0 + offb]);                      \
      }                                                                            \
      if (nhc != hc) {                                                             \
        _Pragma("unroll")                                                          \
        for (int m = 0; m < 8; ++m)                                                \
          _Pragma("unroll")                                                        \
          for (int c = 0; c < 2; ++c)                                              \
            hf2[m][c].s = *(const us8*)(                                           \
                &hT[m >> 1][(m & 1) * 16 + l15][(2 * nhc + c) * 32 + g * 8]);      \
      }                                                                            \
    }                                                                              \
    f = nf;                                                                        \
    hc = nhc;                                                                      \
    ++tt;                                                                          \
  }

  for (int p = 0; p < NT / 2; ++p) {
    TILE_BODY(xqA, xqB);
    TILE_BODY(xqB, xqA);
  }
  if (NT & 1) TILE_BODY(xqA, xqB);
#undef TILE_BODY

  // ---- epilogue: relu(acc+bias); o<128 -> h for next layer; else d-sums
  const float bv = bias[w * 16 + l15];

  if (LAYER < 2 && w < 8) {  // h half (o in [0,128))
    const int o = w * 16 + l15;
    #pragma unroll
    for (int m = 0; m < 8; ++m)
      #pragma unroll
      for (int r = 0; r < 4; ++r) {
        int row = m * 16 + g * 4 + r;  // C/D: row=(lane>>4)*4+reg, col=lane&15
        int s = row >> 5, d = row & 31;
        float v = fmaxf(acc[m][r] + bv, 0.f);
        hout[(((bbase + s) * 32 + d) << 7) + o] = f32_to_f16u(v);
      }
  } else {  // finals: sum over d per sample, store fsum[b][j]
    float sub[4] = {0.f, 0.f, 0.f, 0.f};
    #pragma unroll
    for (int m = 0; m < 8; ++m)
      #pragma unroll
      for (int r = 0; r < 4; ++r)
        sub[m >> 1] += fmaxf(acc[m][r] + bv, 0.f);
    #pragma unroll
    for (int s = 0; s < 4; ++s) {
      sub[s] += __shfl_xor(sub[s], 16);
      sub[s] += __shfl_xor(sub[s], 32);
    }
    if (lane < 16) {
      int o = w * 16 + l15;
      int j = (LAYER == 0) ? (o - 128) : ((LAYER == 1) ? o : (256 + o));
      #pragma unroll
      for (int s = 0; s < 4; ++s) fsum[(bbase + s) * 512 + j] = sub[s];
    }
  }
}

// ---------------- finalize: out[b] = fc_b + sum_j fsum[b][j]*fc_w[j] ----------
__global__ void finalize(const float* __restrict__ fsum, const float* __restrict__ fc_w,
                         const float* __restrict__ fc_b, float* __restrict__ out) {
  int b = blockIdx.x;
  int lane = threadIdx.x;  // 64
  const float* fs = fsum + (size_t)b * 512;
  float s = 0.f;
  #pragma unroll
  for (int k = 0; k < 8; ++k) {
    int j = k * 64 + lane;
    s += fs[j] * fc_w[j];
  }
  #pragma unroll
  for (int off = 32; off; off >>= 1) s += __shfl_xor(s, off);
  if (lane == 0) out[b] = s + fc_b[0];
}

extern "C" void kernel_launch(void* const* d_in, const int* in_sizes, int n_in,
                              void* d_out, int out_size, void* d_ws, size_t ws_size,
                              hipStream_t stream) {
  const float* x = (const float*)d_in[0];
  const float* W0 = (const float*)d_in[1];
  const float* b0 = (const float*)d_in[2];
  const float* W1 = (const float*)d_in[3];
  const float* b1 = (const float*)d_in[4];
  const float* W2 = (const float*)d_in[5];
  const float* b2 = (const float*)d_in[6];
  const float* fc_w = (const float*)d_in[7];
  const float* fc_b = (const float*)d_in[8];
  float* out = (float*)d_out;

  char* ws = (char*)d_ws;
  size_t oWT0 = 0;
  size_t oWT1 = oWT0 + (size_t)256 * 2496 * 2;
  size_t oWT2 = oWT1 + (size_t)256 * 4992 * 2;
  size_t oH = oWT2 + (size_t)256 * 4992 * 2;
  size_t oFS = oH + (size_t)1024 * 32 * 128 * 2;
  size_t oXG = oFS + (size_t)1024 * 512 * 4;
  u16* WT0 = (u16*)(ws + oWT0);
  u16* WT1 = (u16*)(ws + oWT1);
  u16* WT2 = (u16*)(ws + oWT2);
  u16* hbuf = (u16*)(ws + oH);
  float* fsum = (float*)(ws + oFS);
  u16* xg = (u16*)(ws + oXG);  // 256*4992*2 = 2.56 MB

  prep_wt<<<1560, 256, 0, stream>>>(W0, W1, W2, WT0, WT1, WT2);
  prep_xg<<<256, 256, 0, stream>>>(x, xg);
  cin_layer<0><<<256, 1024, 0, stream>>>(x, nullptr, WT0, xg, b0, hbuf, fsum);
  cin_layer<1><<<256, 1024, 0, stream>>>(x, hbuf, WT1, xg, b1, hbuf, fsum);
  cin_layer<2><<<256, 1024, 0, stream>>>(x, hbuf, WT2, xg, b2, nullptr, fsum);
  finalize<<<1024, 64, 0, stream>>>(fsum, fc_w, fc_b, out);
}

// Round 20
// 193.837 us; speedup vs baseline: 1.3744x; 1.3416x over previous
//
#include <hip/hip_runtime.h>
#include <stdint.h>

// CIN (xDeepFM) forward, MI355X f16-MFMA implementation. Round 20 (FINAL):
// = Round 14, the best verified configuration (193.35us, absmax 2.0).
// Session summary: r19's output-side-scale refactor had a coordinate bug
// (C/D row map is g*4+r, not l15) whose fix costs ~270 VGPRs (spill).
// Eight distinct schedules all pin at MfmaUtil 42-45% -> per-wave issue
// serialization at 2 waves/SIMD is the practical plateau of this structure;
// occupancy levers are blocked by hipcc launch-bounds VGPR capping
// (arg>=2 at 512thr is safe; 1024thr or arg=4 force a 64-reg cap + spill).
// Structure: xg global xs path (op_sel f16 broadcast), barrier-free K-loop
// (wave-private wtile slices, gload_lds(16B), XOR swizzle, reg-pipelined fr),
// wave-staggered f-order + setprio, 256 blocks x 512 thr.
// Layers: out[b,d,o] = relu(bias[o] + sum_{f,h'} x0[b,f,d]*h[b,h',d]*W[f*Hp+h',o])
//   layer0: Hp=39 (pad 64), layers1/2: Hp=128. B=1024, F=39, D=32, N=256.

typedef unsigned int u32;
typedef unsigned short u16;
typedef __attribute__((ext_vector_type(8))) unsigned short us8;
typedef __attribute__((ext_vector_type(8))) _Float16 half8;
typedef __attribute__((ext_vector_type(4))) float f32x4;

__device__ __forceinline__ u16 f32_to_f16u(float f) {
  union { _Float16 h; u16 u; } c;
  c.h = (_Float16)f;
  return c.u;
}
// a.{lo,hi} * broadcast(b.lo)
__device__ __forceinline__ u32 pkmul_blo(u32 a, u32 b) {
  u32 r;
  asm("v_pk_mul_f16 %0, %1, %2 op_sel:[0,0] op_sel_hi:[1,0]" : "=v"(r) : "v"(a), "v"(b));
  return r;
}
// a.{lo,hi} * broadcast(b.hi)
__device__ __forceinline__ u32 pkmul_bhi(u32 a, u32 b) {
  u32 r;
  asm("v_pk_mul_f16 %0, %1, %2 op_sel:[0,1] op_sel_hi:[1,1]" : "=v"(r) : "v"(a), "v"(b));
  return r;
}
__device__ __forceinline__ void gload16(const u16* g, u16* l) {
  __builtin_amdgcn_global_load_lds((const __attribute__((address_space(1))) u32*)g,
                                   (__attribute__((address_space(3))) u32*)l, 16, 0, 0);
}
__device__ __forceinline__ void wait_vm0_sb() {
  asm volatile("s_waitcnt vmcnt(0)" ::: "memory");
  __builtin_amdgcn_sched_barrier(0);
}

// ---------------- prep: W (K,256) f32 -> WT (256, KPAD) f16, transposed ------
__global__ void prep_wt(const float* __restrict__ W0, const float* __restrict__ W1,
                        const float* __restrict__ W2, u16* __restrict__ WT0,
                        u16* __restrict__ WT1, u16* __restrict__ WT2) {
  int blk = blockIdx.x;
  const float* W;
  u16* WT;
  int KPAD, kp0;
  bool l0 = false;
  if (blk < 312) { W = W0; WT = WT0; KPAD = 2496; kp0 = blk * 8; l0 = true; }
  else if (blk < 936) { W = W1; WT = WT1; KPAD = 4992; kp0 = (blk - 312) * 8; }
  else { W = W2; WT = WT2; KPAD = 4992; kp0 = (blk - 936) * 8; }

  __shared__ u16 lds[8][257];
  int t = threadIdx.x;  // 256 = n
  #pragma unroll
  for (int kk = 0; kk < 8; ++kk) {
    int kp = kp0 + kk;
    float v;
    if (l0) {
      int f = kp >> 6, hh = kp & 63;
      v = (hh < 39) ? W[(f * 39 + hh) * 256 + t] : 0.f;
    } else {
      v = W[kp * 256 + t];
    }
    lds[kk][t] = f32_to_f16u(v);
  }
  __syncthreads();
  us8 o;
  #pragma unroll
  for (int kk = 0; kk < 8; ++kk) o[kk] = lds[kk][t];
  *(us8*)(&WT[(size_t)t * KPAD + kp0]) = o;
}

// ---------------- prep: x -> xg[bgroup][dl(16)][f(39)][m(8)] f16 -------------
// xg value at (bb,dl,f,m) = f16(x[bb*4 + (m>>1)][f][(m&1)*16 + dl])
__global__ void prep_xg(const float* __restrict__ x, u16* __restrict__ xg) {
  int bb = blockIdx.x;  // 0..255
  int t = threadIdx.x;  // 256
  for (int idx = t; idx < 4992; idx += 256) {
    int dl = idx / 312;
    int rem = idx - dl * 312;
    int f = rem >> 3, m = rem & 7;
    float v = x[(size_t)(bb * 4 + (m >> 1)) * 1248 + f * 32 + (m & 1) * 16 + dl];
    xg[(size_t)bb * 4992 + idx] = f32_to_f16u(v);
  }
}

// ---------------- main layer kernel ------------------------------------------
// grid 256 x 512 threads. Block: 4 samples (M=128 rows), 8 waves each covering
// all 128 rows x its own 32-col slice. K-tile = 64, dbuf LDS, no inner barriers.
// Wave w iterates f in rotated order starting at (w*5)%39.
template <int LAYER>
__global__ __launch_bounds__(512, 2) void cin_layer(
    const float* __restrict__ x, const u16* __restrict__ hin,
    const u16* __restrict__ WT, const u16* __restrict__ xg,
    const float* __restrict__ bias, u16* __restrict__ hout,
    float* __restrict__ fsum) {
  constexpr int HPAD = (LAYER == 0) ? 64 : 128;
  constexpr int HROW = HPAD + 8;
  constexpr int KPAD = 39 * HPAD;
  constexpr int HC2 = HPAD / 64;  // k64 tiles per f
  constexpr int NT = 39 * HC2;

  __shared__ __align__(16) u16 wtile[2][256 * 64];  // [n][64k] swizzled, dbuf
  __shared__ __align__(16) u16 hT[4][32][HROW];     // h^T f16 [b'][d][h']

  const int tid = threadIdx.x;
  const int bbase = blockIdx.x * 4;

  // ---- stage hT (from x for layer 0, from hbuf otherwise)
  if (LAYER == 0) {
    for (int idx = tid; idx < 4 * 1248; idx += 512) {
      int b = idx / 1248;
      int rem = idx - b * 1248;
      int f = rem >> 5, d = rem & 31;
      hT[b][d][f] = f32_to_f16u(x[(bbase + b) * 1248 + rem]);
    }
    for (int idx = tid; idx < 4 * 32 * 25; idx += 512) {  // zero h' in [39,64)
      int b = idx / 800;
      int rem = idx - b * 800;
      int d = rem / 25, p = rem - d * 25;
      hT[b][d][39 + p] = 0;
    }
  } else {
    for (int idx = tid; idx < 4 * 32 * 16; idx += 512) {  // h_buf f16 [b][d][128]
      int b = idx >> 9, rem = idx & 511;
      int d = rem >> 4, c = rem & 15;
      us8 v = *(const us8*)(&hin[(((bbase + b) * 32 + d) << 7) + c * 8]);
      *(us8*)(&hT[b][d][c * 8]) = v;
    }
  }

  const int lane = tid & 63;
  const int w = tid >> 6;  // wave 0..7 -> 32-col slice
  const int l15 = lane & 15;
  const int g = lane >> 4;
  const int off = (w * 5) % 39;  // per-wave f-rotation (stagger)

  // staging per-lane source (inverse-swizzle): lane covers row n, 16B slot
  const int nloc = lane >> 3, slot = lane & 7;
  const int qq = slot ^ nloc;  // data chunk index held at this slot
  const u16* wsrc = WT + (size_t)(w * 32 + nloc) * KPAD + qq * 8;

  // B-read bases (swizzled): row n = w*32 + nt*16 + l15, n&7 == l15&7
  const int xorm = (l15 & 7) * 8;       // u16 units
  const int rB0 = (w * 32 + l15) * 64;  // nt=0 row base
  const u16* xrow = xg + (size_t)blockIdx.x * 4992 + l15 * 312;

  f32x4 acc[8][2];
  #pragma unroll
  for (int m = 0; m < 8; ++m)
    #pragma unroll
    for (int n = 0; n < 2; ++n) acc[m][n] = (f32x4){0.f, 0.f, 0.f, 0.f};

  // prologue: stage this wave's first tile (f=off, hc=0) into buf 0
  {
    const int koff0 = off * HPAD;
    u16* dst = &wtile[0][(w * 32) * 64];
    #pragma unroll
    for (int j = 0; j < 4; ++j)
      gload16(wsrc + (size_t)j * 8 * KPAD + koff0, dst + j * 8 * 64);
  }
  __syncthreads();  // covers hT ds-writes AND tile0 (vmcnt0+lgkmcnt0)

  union HF { u32 u[4]; half8 h; us8 s; };
  union XQ { u32 u[4]; us8 s; };

  // chunk-0 h fragments (reused across the 39-f loop)
  HF hf2[8][2];
  #pragma unroll
  for (int m = 0; m < 8; ++m)
    #pragma unroll
    for (int c = 0; c < 2; ++c)
      hf2[m][c].s = *(const us8*)(&hT[m >> 1][(m & 1) * 16 + l15][c * 32 + g * 8]);

  // preload tile-0 B-fragments (from LDS) and xs (from global)
  HF fr[2][2];
  XQ xqA, xqB;
  #pragma unroll
  for (int c = 0; c < 2; ++c) {
    const int offb = (c * 32 + g * 8) ^ xorm;
    fr[c][0].s = *(const us8*)(&wtile[0][rB0 + offb]);
    fr[c][1].s = *(const us8*)(&wtile[0][rB0 + 16 * 64 + offb]);
  }
  xqA.s = *(const us8*)(xrow + off * 8);  // f=off

  int fi = 0, f = off, hc = 0, tt = 0;

#define TILE_BODY(XC, XN)                                                          \
  {                                                                                \
    const int buf = tt & 1;                                                        \
    const bool more = (tt + 1 < NT);                                               \
    int nfi = fi + 1, nf = f + 1, nhc = hc;                                        \
    if (nfi == 39) { nfi = 0; nf = off; ++nhc; }                                   \
    else if (nf == 39) { nf = 0; }                                                 \
    if (more) {                                                                    \
      const int koff = nf * HPAD + nhc * 64;                                       \
      u16* dst = &wtile[buf ^ 1][(w * 32) * 64];                                   \
      _Pragma("unroll")                                                            \
      for (int j = 0; j < 4; ++j)                                                  \
        gload16(wsrc + (size_t)j * 8 * KPAD + koff, dst + j * 8 * 64);             \
      XN.s = *(const us8*)(xrow + nf * 8);                                         \
      __builtin_amdgcn_sched_barrier(0);                                           \
    }                                                                              \
    __builtin_amdgcn_s_setprio(1);                                                 \
    _Pragma("unroll")                                                              \
    for (int c = 0; c < 2; ++c) {                                                  \
      _Pragma("unroll")                                                            \
      for (int m = 0; m < 8; ++m) {                                                \
        HF a;                                                                      \
        _Pragma("unroll")                                                          \
        for (int i = 0; i < 4; ++i)                                                \
          a.u[i] = (m & 1) ? pkmul_bhi(hf2[m][c].u[i], XC.u[m >> 1])               \
                           : pkmul_blo(hf2[m][c].u[i], XC.u[m >> 1]);              \
        acc[m][0] = __builtin_amdgcn_mfma_f32_16x16x32_f16(a.h, fr[c][0].h,        \
                                                           acc[m][0], 0, 0, 0);    \
        acc[m][1] = __builtin_amdgcn_mfma_f32_16x16x32_f16(a.h, fr[c][1].h,        \
                                                           acc[m][1], 0, 0, 0);    \
      }                                                                            \
    }                                                                              \
    __builtin_amdgcn_s_setprio(0);                                                 \
    if (more) {                                                                    \
      wait_vm0_sb();                                                               \
      _Pragma("unroll")                                                            \
      for (int c = 0; c < 2; ++c) {                                                \
        const int offb = (c * 32 + g * 8) ^ xorm;                                  \
        fr[c][0].s = *(const us8*)(&wtile[buf ^ 1][rB0 + offb]);                   \
        fr[c][1].s = *(const us8*)(&wtile[buf ^ 1][rB0 + 16 * 64 + offb]);         \
      }                                                                            \
      if (nhc != hc) {                                                             \
        _Pragma("unroll")                                                          \
        for (int m = 0; m < 8; ++m)                                                \
          _Pragma("unroll")                                                        \
          for (int c = 0; c < 2; ++c)                                              \
            hf2[m][c].s = *(const us8*)(                                           \
                &hT[m >> 1][(m & 1) * 16 + l15][(2 * nhc + c) * 32 + g * 8]);      \
      }                                                                            \
    }                                                                              \
    fi = nfi;                                                                      \
    f = nf;                                                                        \
    hc = nhc;                                                                      \
    ++tt;                                                                          \
  }

  for (int p = 0; p < NT / 2; ++p) {
    TILE_BODY(xqA, xqB);
    TILE_BODY(xqB, xqA);
  }
  if (NT & 1) TILE_BODY(xqA, xqB);
#undef TILE_BODY

  // ---- epilogue: relu(acc+bias); o<128 -> h for next layer; else d-sums
  float bv[2];
  #pragma unroll
  for (int nt = 0; nt < 2; ++nt) bv[nt] = bias[w * 32 + nt * 16 + l15];

  if (LAYER < 2 && w < 4) {  // h half (o in [0,128))
    #pragma unroll
    for (int m = 0; m < 8; ++m)
      #pragma unroll
      for (int nt = 0; nt < 2; ++nt) {
        int o = w * 32 + nt * 16 + l15;
        #pragma unroll
        for (int r = 0; r < 4; ++r) {
          int row = m * 16 + g * 4 + r;  // C/D: row=(lane>>4)*4+reg, col=lane&15
          int s = row >> 5, d = row & 31;
          float v = fmaxf(acc[m][nt][r] + bv[nt], 0.f);
          hout[(((bbase + s) * 32 + d) << 7) + o] = f32_to_f16u(v);
        }
      }
  } else {  // finals: sum over d per sample, store fsum[b][j]
    #pragma unroll
    for (int nt = 0; nt < 2; ++nt) {
      float sub[4] = {0.f, 0.f, 0.f, 0.f};
      #pragma unroll
      for (int m = 0; m < 8; ++m)
        #pragma unroll
        for (int r = 0; r < 4; ++r)
          sub[m >> 1] += fmaxf(acc[m][nt][r] + bv[nt], 0.f);
      #pragma unroll
      for (int s = 0; s < 4; ++s) {
        sub[s] += __shfl_xor(sub[s], 16);
        sub[s] += __shfl_xor(sub[s], 32);
      }
      if (lane < 16) {
        int o = w * 32 + nt * 16 + l15;
        int j = (LAYER == 0) ? (o - 128) : ((LAYER == 1) ? o : (256 + o));
        #pragma unroll
        for (int s = 0; s < 4; ++s) fsum[(bbase + s) * 512 + j] = sub[s];
      }
    }
  }
}

// ---------------- finalize: out[b] = fc_b + sum_j fsum[b][j]*fc_w[j] ----------
__global__ void finalize(const float* __restrict__ fsum, const float* __restrict__ fc_w,
                         const float* __restrict__ fc_b, float* __restrict__ out) {
  int b = blockIdx.x;
  int lane = threadIdx.x;  // 64
  const float* fs = fsum + (size_t)b * 512;
  float s = 0.f;
  #pragma unroll
  for (int k = 0; k < 8; ++k) {
    int j = k * 64 + lane;
    s += fs[j] * fc_w[j];
  }
  #pragma unroll
  for (int off = 32; off; off >>= 1) s += __shfl_xor(s, off);
  if (lane == 0) out[b] = s + fc_b[0];
}

extern "C" void kernel_launch(void* const* d_in, const int* in_sizes, int n_in,
                              void* d_out, int out_size, void* d_ws, size_t ws_size,
                              hipStream_t stream) {
  const float* x = (const float*)d_in[0];
  const float* W0 = (const float*)d_in[1];
  const float* b0 = (const float*)d_in[2];
  const float* W1 = (const float*)d_in[3];
  const float* b1 = (const float*)d_in[4];
  const float* W2 = (const float*)d_in[5];
  const float* b2 = (const float*)d_in[6];
  const float* fc_w = (const float*)d_in[7];
  const float* fc_b = (const float*)d_in[8];
  float* out = (float*)d_out;

  char* ws = (char*)d_ws;
  size_t oWT0 = 0;
  size_t oWT1 = oWT0 + (size_t)256 * 2496 * 2;
  size_t oWT2 = oWT1 + (size_t)256 * 4992 * 2;
  size_t oH = oWT2 + (size_t)256 * 4992 * 2;
  size_t oFS = oH + (size_t)1024 * 32 * 128 * 2;
  size_t oXG = oFS + (size_t)1024 * 512 * 4;
  u16* WT0 = (u16*)(ws + oWT0);
  u16* WT1 = (u16*)(ws + oWT1);
  u16* WT2 = (u16*)(ws + oWT2);
  u16* hbuf = (u16*)(ws + oH);
  float* fsum = (float*)(ws + oFS);
  u16* xg = (u16*)(ws + oXG);  // 256*4992*2 = 2.56 MB

  prep_wt<<<1560, 256, 0, stream>>>(W0, W1, W2, WT0, WT1, WT2);
  prep_xg<<<256, 256, 0, stream>>>(x, xg);
  cin_layer<0><<<256, 512, 0, stream>>>(x, nullptr, WT0, xg, b0, hbuf, fsum);
  cin_layer<1><<<256, 512, 0, stream>>>(x, hbuf, WT1, xg, b1, hbuf, fsum);
  cin_layer<2><<<256, 512, 0, stream>>>(x, hbuf, WT2, xg, b2, nullptr, fsum);
  finalize<<<1024, 64, 0, stream>>>(fsum, fc_w, fc_b, out);
}